// Round 1
// baseline (1745.851 us; speedup 1.0000x reference)
//
#include <hip/hip_runtime.h>
#include <stdint.h>

#define N_PTS  1000000
#define FDIM   128
#define NSEG   50000
#define NSTEPS 3

typedef __attribute__((ext_vector_type(4))) float f32x4;
typedef __attribute__((ext_vector_type(8))) short bf16x8;

__device__ __forceinline__ short f2bf(float f) {
  uint32_t u = __float_as_uint(f);
  return (short)((u + 0x7fffu + ((u >> 16) & 1u)) >> 16);   // RNE f32->bf16
}
__device__ __forceinline__ float bf2f(short s) {
  return __uint_as_float(((uint32_t)(uint16_t)s) << 16);
}
__device__ __forceinline__ float sigm(float x) { return 1.f / (1.f + __expf(-x)); }
__device__ __forceinline__ float ftanh(float x) {
  x = fminf(fmaxf(x, -15.f), 15.f);        // avoid inf/inf
  float t = __expf(2.f * x);
  return (t - 1.f) / (t + 1.f);
}

// ---------------- zero-init (h0,h1,c contiguous) + d_out --------------------
__global__ void k_zero(float* a, long na, float* b, long nb) {
  const f32x4 vz = {0.f, 0.f, 0.f, 0.f};
  const long stride = (long)gridDim.x * blockDim.x * 4;
  const long i0 = ((long)blockIdx.x * blockDim.x + threadIdx.x) * 4;
  for (long i = i0; i < na; i += stride) *(f32x4*)(a + i) = vz;
  for (long i = i0; i < nb; i += stride) *(f32x4*)(b + i) = vz;
}

// ------------- weight prep: bf16 fragment-ordered layouts -------------------
// frag layout for mfma_f32_16x16x32_bf16 B-operand: lane l supplies
// B[k][n] with n = ntile*16 + (l&15), k = kc*32 + (l>>4)*8 + j, j=0..7.
// Stored as [kc][ntile][lane][8] so a wave's 16B reads are lane-consecutive.
__global__ void k_prep(const float* __restrict__ lin_w, const float* __restrict__ w_ih,
                       const float* __restrict__ w_hh, const float* __restrict__ b_ih,
                       const float* __restrict__ b_hh,
                       short* __restrict__ lin_fr, short* __restrict__ wc_fr,
                       float* __restrict__ bias_c) {
  const int tid = blockIdx.x * blockDim.x + threadIdx.x;
  const int stride = gridDim.x * blockDim.x;
  for (int i = tid; i < FDIM * FDIM; i += stride) {         // lin_w: K=128 -> kc 0..3, nt 0..7
    const int j = i & 7, lane = (i >> 3) & 63, fidx = i >> 9;
    const int kc = fidx >> 3, nt = fidx & 7;
    const int n = nt * 16 + (lane & 15);
    const int k = kc * 32 + (lane >> 4) * 8 + j;
    lin_fr[i] = f2bf(lin_w[n * FDIM + k]);
  }
  for (int i = tid; i < 4 * FDIM * 3 * FDIM; i += stride) { // W_cat=[w_ih|w_hh]: K=384 -> kc 0..11, nt 0..31
    const int j = i & 7, lane = (i >> 3) & 63, fidx = i >> 9;
    const int kc = fidx >> 5, nt = fidx & 31;
    const int n = nt * 16 + (lane & 15);
    const int k = kc * 32 + (lane >> 4) * 8 + j;
    const float v = (k < 2 * FDIM) ? w_ih[n * 2 * FDIM + k] : w_hh[n * FDIM + (k - 2 * FDIM)];
    wc_fr[i] = f2bf(v);
  }
  for (int i = tid; i < 4 * FDIM; i += stride) bias_c[i] = b_ih[i] + b_hh[i];
}

// ---------------- segment offsets via binary search (index sorted) ----------
__global__ void k_seg(const int* __restrict__ index, int* __restrict__ seg) {
  const int s = blockIdx.x * blockDim.x + threadIdx.x;
  if (s > NSEG) return;
  int lo = 0, hi = N_PTS;
  while (lo < hi) { const int mid = (lo + hi) >> 1; if (index[mid] < s) lo = mid + 1; else hi = mid; }
  seg[s] = lo;
}

// ---------------- xh = bf16(x @ lin_w^T + lin_b) ----------------------------
// 4 waves x 16 rows = 64 rows/block; B (lin_w) staged frag-ordered in LDS.
__global__ __launch_bounds__(256) void k_xh(const float* __restrict__ x,
                                            const short* __restrict__ lin_fr,
                                            const float* __restrict__ lin_b,
                                            short* __restrict__ xh) {
  __shared__ short wlds[FDIM * FDIM];
  __shared__ float blds[FDIM];
  {
    const int t = threadIdx.x;
    const int4* src = (const int4*)lin_fr;
    int4* dst = (int4*)wlds;
#pragma unroll
    for (int i = 0; i < 8; ++i) dst[t + 256 * i] = src[t + 256 * i];
    if (t < FDIM) blds[t] = lin_b[t];
  }
  __syncthreads();
  const int lane = threadIdx.x & 63;
  const int wv = threadIdx.x >> 6;
  const int lrow = lane & 15, kgrp = lane >> 4;
  const long row0 = (long)blockIdx.x * 64 + wv * 16;

  // A fragments: lane l holds x[row0 + (l&15)][kc*32 + (l>>4)*8 + j]
  bf16x8 afr[4];
  const float* xrow = x + (row0 + lrow) * FDIM;
#pragma unroll
  for (int kc = 0; kc < 4; ++kc) {
    const float* p = xrow + kc * 32 + kgrp * 8;
    const f32x4 v0 = *(const f32x4*)p;
    const f32x4 v1 = *(const f32x4*)(p + 4);
    bf16x8 a;
    a[0] = f2bf(v0[0]); a[1] = f2bf(v0[1]); a[2] = f2bf(v0[2]); a[3] = f2bf(v0[3]);
    a[4] = f2bf(v1[0]); a[5] = f2bf(v1[1]); a[6] = f2bf(v1[2]); a[7] = f2bf(v1[3]);
    afr[kc] = a;
  }
  const bf16x8* wf = (const bf16x8*)wlds;
  f32x4 acc[8];
  const f32x4 vz = {0.f, 0.f, 0.f, 0.f};
#pragma unroll
  for (int nt = 0; nt < 8; ++nt) acc[nt] = vz;
#pragma unroll
  for (int kc = 0; kc < 4; ++kc)
#pragma unroll
    for (int nt = 0; nt < 8; ++nt)
      acc[nt] = __builtin_amdgcn_mfma_f32_16x16x32_bf16(afr[kc], wf[(kc * 8 + nt) * 64 + lane],
                                                        acc[nt], 0, 0, 0);
  // D: row = kgrp*4 + r, col = nt*16 + lrow
#pragma unroll
  for (int nt = 0; nt < 8; ++nt) {
    const int col = nt * 16 + lrow;
    const float b = blds[col];
#pragma unroll
    for (int r = 0; r < 4; ++r)
      xh[(row0 + kgrp * 4 + r) * FDIM + col] = f2bf(acc[nt][r] + b);
  }
}

// ---------------- fused LSTM cell -------------------------------------------
// gates[m][n] = [q_star|h_prev][m][:384] @ W_cat[n][:384]^T + bias; then
// activations + c/h update fused. 8 waves: (wv&1)=16-row group, (wv>>1)=j-range.
// Block covers 32 rows x all 512 gate cols -> each thread owns i,f,g,o at (m,j).
__global__ __launch_bounds__(512) void k_lstm(const float* __restrict__ qstar,
                                              const float* __restrict__ hprev,
                                              float* __restrict__ hnext,
                                              float* __restrict__ c,
                                              const short* __restrict__ wfr,
                                              const float* __restrict__ bias) {
  const int t = threadIdx.x;
  const int lane = t & 63, wv = t >> 6;
  const int lrow = lane & 15, kgrp = lane >> 4;
  const int jg = wv >> 1;
  const int row0 = blockIdx.x * 32 + (wv & 1) * 16;
  const int mld = min(row0 + lrow, NSEG - 1);
  const bf16x8* wf = (const bf16x8*)wfr;
  const f32x4 vz = {0.f, 0.f, 0.f, 0.f};
  f32x4 acc[4][2];
#pragma unroll
  for (int g = 0; g < 4; ++g) { acc[g][0] = vz; acc[g][1] = vz; }
#pragma unroll
  for (int kc = 0; kc < 12; ++kc) {
    const int k = kc * 32 + kgrp * 8;
    const float* p = (kc < 8) ? (qstar + (long)mld * 256 + k)
                              : (hprev + (long)mld * 128 + (k - 256));
    const f32x4 v0 = *(const f32x4*)p;
    const f32x4 v1 = *(const f32x4*)(p + 4);
    bf16x8 a;
    a[0] = f2bf(v0[0]); a[1] = f2bf(v0[1]); a[2] = f2bf(v0[2]); a[3] = f2bf(v0[3]);
    a[4] = f2bf(v1[0]); a[5] = f2bf(v1[1]); a[6] = f2bf(v1[2]); a[7] = f2bf(v1[3]);
#pragma unroll
    for (int g = 0; g < 4; ++g)
#pragma unroll
      for (int p2 = 0; p2 < 2; ++p2)
        acc[g][p2] = __builtin_amdgcn_mfma_f32_16x16x32_bf16(
            a, wf[(kc * 32 + g * 8 + jg * 2 + p2) * 64 + lane], acc[g][p2], 0, 0, 0);
  }
#pragma unroll
  for (int p2 = 0; p2 < 2; ++p2) {
    const int j = (jg * 2 + p2) * 16 + lrow;
    const float bi = bias[j], bff = bias[128 + j], bg = bias[256 + j], bo = bias[384 + j];
#pragma unroll
    for (int r = 0; r < 4; ++r) {
      const int m = row0 + kgrp * 4 + r;
      if (m < NSEG) {
        const float gi = acc[0][p2][r] + bi;
        const float gf = acc[1][p2][r] + bff;
        const float gg = acc[2][p2][r] + bg;
        const float go = acc[3][p2][r] + bo;
        const long idx = (long)m * FDIM + j;
        const float cn = sigm(gf) * c[idx] + sigm(gi) * ftanh(gg);
        c[idx] = cn;
        hnext[idx] = sigm(go) * ftanh(cn);
      }
    }
  }
}

// ---------------- fused segment attention -----------------------------------
// One block per segment (index sorted -> contiguous rows). Online softmax in
// chunks of 256 rows; r accumulated per-column, rows split across 2 halves.
#define CHUNK 256
__global__ __launch_bounds__(256) void k_attn(const short* __restrict__ xh,
                                              const float* __restrict__ h,
                                              const int* __restrict__ seg,
                                              float* __restrict__ qstar) {
  const int s = blockIdx.x;
  const int t = threadIdx.x;
  const int lane = t & 63, wv = t >> 6;
  const int col = t & 127, half = t >> 7;
  const int beg = seg[s], end = seg[s + 1];
  __shared__ float qv[FDIM];
  __shared__ float ew[CHUNK];
  __shared__ float reda[4], redb[4];
  __shared__ float rhalf[FDIM];
  if (t < FDIM) qv[t] = h[(long)s * FDIM + t];
  __syncthreads();
  float racc = 0.f, m_run = -1e30f, l_run = 0.f;
  for (int base = beg; base < end; base += CHUNK) {
    const int cnt = min(CHUNK, end - base);
    // e_i = dot(xh[i], q): wave per row, 2 cols/lane, shfl tree reduce
    for (int i = wv; i < cnt; i += 4) {
      const uint32_t u = *(const uint32_t*)(xh + (long)(base + i) * FDIM + 2 * lane);
      float p = bf2f((short)(u & 0xffffu)) * qv[2 * lane]
              + bf2f((short)(u >> 16)) * qv[2 * lane + 1];
      p += __shfl_xor(p, 32); p += __shfl_xor(p, 16); p += __shfl_xor(p, 8);
      p += __shfl_xor(p, 4);  p += __shfl_xor(p, 2);  p += __shfl_xor(p, 1);
      if (lane == 0) ew[i] = p;
    }
    __syncthreads();
    // chunk max
    float mx = (t < cnt) ? ew[t] : -1e30f;
    mx = fmaxf(mx, __shfl_xor(mx, 32)); mx = fmaxf(mx, __shfl_xor(mx, 16));
    mx = fmaxf(mx, __shfl_xor(mx, 8));  mx = fmaxf(mx, __shfl_xor(mx, 4));
    mx = fmaxf(mx, __shfl_xor(mx, 2));  mx = fmaxf(mx, __shfl_xor(mx, 1));
    if (lane == 0) reda[wv] = mx;
    __syncthreads();
    const float m_new = fmaxf(m_run, fmaxf(fmaxf(reda[0], reda[1]), fmaxf(reda[2], reda[3])));
    const float scl = __expf(m_run - m_new);   // 0 on first chunk
    float ls = 0.f;
    if (t < cnt) { const float w = __expf(ew[t] - m_new); ew[t] = w; ls = w; }
    ls += __shfl_xor(ls, 32); ls += __shfl_xor(ls, 16); ls += __shfl_xor(ls, 8);
    ls += __shfl_xor(ls, 4);  ls += __shfl_xor(ls, 2);  ls += __shfl_xor(ls, 1);
    if (lane == 0) redb[wv] = ls;
    __syncthreads();
    l_run = l_run * scl + (redb[0] + redb[1] + redb[2] + redb[3]);
    // r accumulation: thread owns col (t&127); halves take even/odd rows
    racc *= scl;
    for (int i = half; i < cnt; i += 2)
      racc += ew[i] * bf2f(xh[(long)(base + i) * FDIM + col]);
    m_run = m_new;
    __syncthreads();
  }
  if (half == 1) rhalf[col] = racc;
  __syncthreads();
  if (half == 0) {
    const float r = (racc + rhalf[col]) / (l_run + 1e-16f);
    float* o = qstar + (long)s * (2 * FDIM);
    o[col] = qv[col];        // q part = h_new
    o[FDIM + col] = r;       // r part
  }
}

// ---------------------------------------------------------------------------
extern "C" void kernel_launch(void* const* d_in, const int* in_sizes, int n_in,
                              void* d_out, int out_size, void* d_ws, size_t ws_size,
                              hipStream_t stream) {
  const float* x     = (const float*)d_in[0];
  const int*   index = (const int*)d_in[1];
  const float* lin_w = (const float*)d_in[3];
  const float* lin_b = (const float*)d_in[4];
  const float* w_ih  = (const float*)d_in[5];
  const float* w_hh  = (const float*)d_in[6];
  const float* b_ih  = (const float*)d_in[7];
  const float* b_hh  = (const float*)d_in[8];

  char* ws = (char*)d_ws;
  size_t o = 0;
  short* xh     = (short*)(ws + o); o += (size_t)N_PTS * FDIM * 2;   // 256 MB bf16
  float* h0     = (float*)(ws + o); o += (size_t)NSEG * FDIM * 4;    // h0,h1,c contiguous
  float* h1     = (float*)(ws + o); o += (size_t)NSEG * FDIM * 4;
  float* c      = (float*)(ws + o); o += (size_t)NSEG * FDIM * 4;
  short* lin_fr = (short*)(ws + o); o += (size_t)FDIM * FDIM * 2;
  short* wc_fr  = (short*)(ws + o); o += (size_t)4 * FDIM * 3 * FDIM * 2;
  float* bias_c = (float*)(ws + o); o += (size_t)4 * FDIM * 4;
  int*   seg    = (int*)(ws + o);   o += (size_t)(NSEG + 1) * 4;

  k_zero<<<1024, 256, 0, stream>>>(h0, (long)3 * NSEG * FDIM, (float*)d_out, (long)NSEG * 2 * FDIM);
  k_prep<<<256, 256, 0, stream>>>(lin_w, w_ih, w_hh, b_ih, b_hh, lin_fr, wc_fr, bias_c);
  k_seg<<<(NSEG + 256) / 256, 256, 0, stream>>>(index, seg);
  k_xh<<<N_PTS / 64, 256, 0, stream>>>(x, lin_fr, lin_b, xh);

  float* hp = h0; float* hn = h1;
  for (int step = 0; step < NSTEPS; ++step) {
    k_lstm<<<(NSEG + 31) / 32, 512, 0, stream>>>((const float*)d_out, hp, hn, c, wc_fr, bias_c);
    k_attn<<<NSEG, 256, 0, stream>>>(xh, hn, seg, (float*)d_out);
    float* tmp = hp; hp = hn; hn = tmp;
  }
}